// Round 5
// baseline (241.693 us; speedup 1.0000x reference)
//
#include <hip/hip_runtime.h>

// CapsuleLayer: B=64, L=512, D=1024, C=32, O=64, 3 routing iters.
// u_hat never materialized:
//   dots[b,l,c] = in[b,l,:]@w_v[b,c,:] + bias_v[b,c]   (w_v[b,c,d] = sum_o fc_w[d,cO+o] v[b,c,o])
//   s_j[b,c,:]  = x_c[b,c,:]@fc_w[:,c,:] + csum[b,c]*fc_b[c,:]   (x_c = sum_l c_w * in)
// All three contractions via mfma_f32_16x16x32_bf16, direct global->fragment
// loads. Layouts: in_bf[b][l][d] bf16 (route A-frags), in_T[b][d][l] bf16
// (xc B-frags), fc_wT[co][d] bf16, c_wT[b][c][l] bf16, x_cb[c][b][d] bf16.
// Prep is split: k_conv (pure stream convert + rowsum) then k_tr (bf16
// tile transpose via u32-packed LDS, XOR-chunk swizzled: no scalar u16 ops).

namespace {
constexpr int Bn = 64, Ln = 512, Dn = 1024, Cn = 32, On = 64, COn = Cn * On;
}

typedef float f32x4 __attribute__((ext_vector_type(4)));
typedef short bf16x8 __attribute__((ext_vector_type(8)));

static __device__ __forceinline__ unsigned short f2bf(float f) {
    unsigned u = __float_as_uint(f);
    u += 0x7fff + ((u >> 16) & 1);   // RNE
    return (unsigned short)(u >> 16);
}

// ---------------------------------------------------------------- conv ------
// in fp32 [b][l][d] -> in_bf bf16 [b][l][d] + rowsum partials [b][lc][d]
__global__ __launch_bounds__(256) void k_conv(const float* __restrict__ in,
                                              short* __restrict__ in_bf,
                                              float* __restrict__ rs_p) {
    __shared__ float4 rs4_sh[4][64];
    int b = blockIdx.y;
    int lc = blockIdx.x >> 2, dc = blockIdx.x & 3;
    int t = threadIdx.x;
    int grp = t >> 6, dq = t & 63;
    float4 rs = make_float4(0.f, 0.f, 0.f, 0.f);
    const float* src = in + ((size_t)b * Ln + lc * 64) * Dn + dc * 256 + dq * 4;
    short* dst = in_bf + ((size_t)b * Ln + lc * 64) * Dn + dc * 256 + dq * 4;
#pragma unroll
    for (int i = 0; i < 16; ++i) {
        int row = grp + 4 * i;
        float4 x = *(const float4*)(src + (size_t)row * Dn);
        rs.x += x.x; rs.y += x.y; rs.z += x.z; rs.w += x.w;
        *(short4*)(dst + (size_t)row * Dn) =
            make_short4((short)f2bf(x.x), (short)f2bf(x.y),
                        (short)f2bf(x.z), (short)f2bf(x.w));
    }
    rs4_sh[grp][dq] = rs;
    __syncthreads();
    if (t < 64) {
        float4 a = rs4_sh[0][t], b2 = rs4_sh[1][t], c2 = rs4_sh[2][t], d2 = rs4_sh[3][t];
        float4 s = make_float4(a.x + b2.x + c2.x + d2.x, a.y + b2.y + c2.y + d2.y,
                               a.z + b2.z + c2.z + d2.z, a.w + b2.w + c2.w + d2.w);
        *(float4*)(rs_p + ((size_t)b * 8 + lc) * Dn + dc * 256 + t * 4) = s;
    }
}

// ---------------------------------------------------------------- tr --------
// in_bf bf16 [b][l][d] -> in_T bf16 [b][d][l], 64x64 tiles.
// l-pairs packed into u32; LDS tile [64 d][36 u32 stride]; column chunk
// (4 u32) XOR-swizzled by (d>>3) so b32 writes are 2-way (free) and b128
// reads are conflict-free. All wide ops, no scalar u16.
__global__ __launch_bounds__(256) void k_tr(const short* __restrict__ in_bf,
                                            short* __restrict__ in_T) {
    __shared__ unsigned tile[64 * 36];   // 9216 B
    int dt = blockIdx.x, lt = blockIdx.y, b = blockIdx.z;
    int l0 = lt * 64, d0 = dt * 64;
    int t = threadIdx.x;
    int d8 = t & 7;        // d-octet 0..7
    int lp = t >> 3;       // l-pair 0..31
    const short* src = in_bf + ((size_t)b * Ln + l0 + 2 * lp) * Dn + d0 + d8 * 8;
    bf16x8 a0 = *(const bf16x8*)src;
    bf16x8 a1 = *(const bf16x8*)(src + Dn);
    int col = lp ^ (d8 << 2);            // swizzle bits [4:2] of column by d8
#pragma unroll
    for (int k = 0; k < 8; ++k) {
        unsigned u = ((unsigned)(unsigned short)a1[k] << 16) |
                     (unsigned)(unsigned short)a0[k];
        tile[(d8 * 8 + k) * 36 + col] = u;
    }
    __syncthreads();
#pragma unroll
    for (int r = 0; r < 2; ++r) {
        int idx = t + 256 * r;
        int d = idx >> 3;                // 0..63
        int q = idx & 7;                 // 4-u32 chunk 0..7
        int qs = q ^ (d >> 3);           // un-swizzle chunk
        uint4 u = *(const uint4*)(&tile[d * 36 + qs * 4]);
        *(uint4*)(in_T + ((size_t)b * Dn + d0 + d) * Ln + l0 + q * 8) = u;
    }
}

// ---------------------------------------------------------------- wprep -----
// fc_w fp32 [d][co] -> fc_wT bf16 [co][d]
__global__ __launch_bounds__(256) void k_wprep(const float* __restrict__ fc_w,
                                               short* __restrict__ fc_wT) {
    __shared__ short tr[64 * 260];      // [d-row][co-col]
    int d0 = blockIdx.x * 64;           // 16
    int co0 = blockIdx.y * 256;         // 8
    int t = threadIdx.x, grp = t >> 6, cq = t & 63;
#pragma unroll
    for (int i = 0; i < 16; ++i) {
        int row = grp + 4 * i;
        float4 x = *(const float4*)(fc_w + (size_t)(d0 + row) * COn + co0 + cq * 4);
        *(short4*)(&tr[row * 260 + cq * 4]) =
            make_short4((short)f2bf(x.x), (short)f2bf(x.y),
                        (short)f2bf(x.z), (short)f2bf(x.w));
    }
    __syncthreads();
#pragma unroll
    for (int i = 0; i < 8; ++i) {
        int idx = t + 256 * i;
        int corow = idx >> 3, slot = idx & 7;
        bf16x8 v;
#pragma unroll
        for (int j = 0; j < 8; ++j) v[j] = tr[(slot * 8 + j) * 260 + corow];
        *(bf16x8*)(fc_wT + (size_t)(co0 + corow) * Dn + d0 + slot * 8) = v;
    }
}

// ---------------------------------------------------------------- rsred -----
__global__ __launch_bounds__(256) void k_rsred(const float* __restrict__ rs_p,
                                               unsigned short* __restrict__ rs_bf) {
    int b = blockIdx.y, d = blockIdx.x * 256 + threadIdx.x;
    float s = 0.f;
#pragma unroll
    for (int lc = 0; lc < 8; ++lc) s += rs_p[((size_t)b * 8 + lc) * Dn + d];
    rs_bf[b * Dn + d] = f2bf(s * (1.0f / 32.0f));
}

// ------------------------------------------------------- s -> squash -> v ---
// Per-c MFMA GEMM: S[64 b][64 o] = X(64x1024)@W_c(1024x64). No LDS.
__global__ __launch_bounds__(256) void k_sv3(const short* __restrict__ xA,
                                             const float* __restrict__ csum_p,
                                             const short* __restrict__ fc_wT,
                                             const float* __restrict__ fc_b,
                                             float* __restrict__ v_out,
                                             float* __restrict__ bias_v,
                                             int mode0) {
    int c = blockIdx.x;
    int t = threadIdx.x, w = t >> 6, lane = t & 63;
    int l15 = lane & 15, lg = lane >> 4;
    const short* A = mode0 ? xA : (xA + (size_t)c * Bn * Dn);   // [b][d]
    const short* Bw = fc_wT + (size_t)c * On * Dn;              // [o][d]
    f32x4 acc[4];
#pragma unroll
    for (int i = 0; i < 4; ++i) acc[i] = {0.f, 0.f, 0.f, 0.f};
    for (int ks = 0; ks < 32; ++ks) {
        int koff = ks * 32 + lg * 8;
        bf16x8 a = *(const bf16x8*)(A + (size_t)(w * 16 + l15) * Dn + koff);
#pragma unroll
        for (int dt = 0; dt < 4; ++dt) {
            bf16x8 bb = *(const bf16x8*)(Bw + (size_t)(dt * 16 + l15) * Dn + koff);
            acc[dt] = __builtin_amdgcn_mfma_f32_16x16x32_bf16(a, bb, acc[dt], 0, 0, 0);
        }
    }
    float fb[4];
#pragma unroll
    for (int dt = 0; dt < 4; ++dt) fb[dt] = fc_b[c * On + dt * 16 + l15];
#pragma unroll
    for (int r = 0; r < 4; ++r) {
        int brow = w * 16 + lg * 4 + r;
        float cs;
        if (mode0) {
            cs = 16.0f;
        } else {
            cs = 0.f;
#pragma unroll
            for (int lt = 0; lt < 8; ++lt) cs += csum_p[((size_t)lt * Bn + brow) * Cn + c];
        }
        float s0 = acc[0][r] + cs * fb[0];
        float s1 = acc[1][r] + cs * fb[1];
        float s2 = acc[2][r] + cs * fb[2];
        float s3 = acc[3][r] + cs * fb[3];
        float sq = s0 * s0 + s1 * s1 + s2 * s2 + s3 * s3;
        sq += __shfl_xor(sq, 1, 64); sq += __shfl_xor(sq, 2, 64);
        sq += __shfl_xor(sq, 4, 64); sq += __shfl_xor(sq, 8, 64);
        float scale = sq / (1.0f + sq) * rsqrtf(sq + 1e-8f);
        float v0 = scale * s0, v1 = scale * s1, v2 = scale * s2, v3 = scale * s3;
        float* vp = v_out + ((size_t)brow * Cn + c) * On;
        vp[0 * 16 + l15] = v0; vp[1 * 16 + l15] = v1;
        vp[2 * 16 + l15] = v2; vp[3 * 16 + l15] = v3;
        float bv = fb[0] * v0 + fb[1] * v1 + fb[2] * v2 + fb[3] * v3;
        bv += __shfl_xor(bv, 1, 64); bv += __shfl_xor(bv, 2, 64);
        bv += __shfl_xor(bv, 4, 64); bv += __shfl_xor(bv, 8, 64);
        if (l15 == 0) bias_v[brow * Cn + c] = bv;
    }
}

// -------------------------------------------------- w_v[b,c,d] projection ---
// fp32 math, bf16 output. grid (8 dtiles, 32 c), block 256.
__global__ __launch_bounds__(256) void k_wv2b(const float* __restrict__ v,
                                              const float* __restrict__ fc_w,
                                              short* __restrict__ w_vb) {
    int dtile = blockIdx.x;   // 0..7
    int c = blockIdx.y;       // 0..31
    int t = threadIdx.x;
    int bg = t & 7;           // b = bg + 8*bi
    int dg = t >> 3;          // d = d0 + dg*4 + dj
    __shared__ float fc_sh[128 * 68];
    __shared__ float v_sh[64 * 68];
    int d0 = dtile * 128;
#pragma unroll
    for (int i = 0; i < 8; ++i) {
        int idx = t + 256 * i;
        int dl = idx >> 4, oq = idx & 15;
        *(float4*)(fc_sh + dl * 68 + oq * 4) =
            *(const float4*)(fc_w + (size_t)(d0 + dl) * COn + c * On + oq * 4);
    }
#pragma unroll
    for (int i = 0; i < 4; ++i) {
        int idx = t + 256 * i;
        int bl = idx >> 4, oq = idx & 15;
        *(float4*)(v_sh + bl * 68 + oq * 4) =
            *(const float4*)(v + ((size_t)bl * Cn + c) * On + oq * 4);
    }
    __syncthreads();

    float acc[8][4];
#pragma unroll
    for (int i = 0; i < 8; ++i)
#pragma unroll
        for (int j = 0; j < 4; ++j) acc[i][j] = 0.f;

#pragma unroll 2
    for (int o = 0; o < 64; o += 4) {
        float4 fc4[4];
#pragma unroll
        for (int dj = 0; dj < 4; ++dj)
            fc4[dj] = *(const float4*)(fc_sh + (dg * 4 + dj) * 68 + o);
#pragma unroll
        for (int bi = 0; bi < 8; ++bi) {
            float4 v4 = *(const float4*)(v_sh + (bg + 8 * bi) * 68 + o);
#pragma unroll
            for (int dj = 0; dj < 4; ++dj) {
                acc[bi][dj] += v4.x * fc4[dj].x + v4.y * fc4[dj].y +
                               v4.z * fc4[dj].z + v4.w * fc4[dj].w;
            }
        }
    }
#pragma unroll
    for (int bi = 0; bi < 8; ++bi) {
        int b = bg + 8 * bi;
        *(short4*)(w_vb + ((size_t)b * Cn + c) * Dn + d0 + dg * 4) =
            make_short4((short)f2bf(acc[bi][0]), (short)f2bf(acc[bi][1]),
                        (short)f2bf(acc[bi][2]), (short)f2bf(acc[bi][3]));
    }
}

// ------------------------------- dots -> b_ij update -> softmax -> c_wT -----
// grid (8 lt, 64 b), 256 thr / 4 waves, wave = 16 l-rows x 32 c. MFMA,
// A-frags straight from in_bf (bf16), B = w_v bf16 rows.
__global__ __launch_bounds__(256) void k_route_m(const short* __restrict__ in_bf,
                                                 const short* __restrict__ w_v,
                                                 const float* __restrict__ bias_v,
                                                 float* __restrict__ b_ij,
                                                 short* __restrict__ c_wT,
                                                 float* __restrict__ csum_p,
                                                 int first) {
    __shared__ short cw_sh[Cn * 68];
    __shared__ float cs_sh[4][Cn];
    int lt = blockIdx.x, b = blockIdx.y;
    int t = threadIdx.x, w = t >> 6, lane = t & 63;
    int l15 = lane & 15, lg = lane >> 4;
    int l0 = lt * 64;
    f32x4 acc0 = {0.f, 0.f, 0.f, 0.f}, acc1 = {0.f, 0.f, 0.f, 0.f};
    const short* Ap = in_bf + ((size_t)b * Ln + l0 + w * 16 + l15) * Dn;
    const short* Bp = w_v + (size_t)b * Cn * Dn;
    for (int ks = 0; ks < 32; ++ks) {
        int koff = ks * 32 + lg * 8;
        bf16x8 a = *(const bf16x8*)(Ap + koff);
        bf16x8 b0 = *(const bf16x8*)(Bp + (size_t)l15 * Dn + koff);
        bf16x8 b1 = *(const bf16x8*)(Bp + (size_t)(l15 + 16) * Dn + koff);
        acc0 = __builtin_amdgcn_mfma_f32_16x16x32_bf16(a, b0, acc0, 0, 0, 0);
        acc1 = __builtin_amdgcn_mfma_f32_16x16x32_bf16(a, b1, acc1, 0, 0, 0);
    }
    float bv0 = bias_v[b * Cn + l15];
    float bv1 = bias_v[b * Cn + l15 + 16];
    float csa0 = 0.f, csa1 = 0.f;
#pragma unroll
    for (int r = 0; r < 4; ++r) {
        int lrow = l0 + w * 16 + lg * 4 + r;
        size_t boff = ((size_t)b * Ln + lrow) * Cn;
        float d0 = acc0[r] + bv0, d1 = acc1[r] + bv1;
        if (!first) { d0 += b_ij[boff + l15]; d1 += b_ij[boff + l15 + 16]; }
        b_ij[boff + l15] = d0;
        b_ij[boff + l15 + 16] = d1;
        float m = fmaxf(d0, d1);
        m = fmaxf(m, __shfl_xor(m, 1, 64)); m = fmaxf(m, __shfl_xor(m, 2, 64));
        m = fmaxf(m, __shfl_xor(m, 4, 64)); m = fmaxf(m, __shfl_xor(m, 8, 64));
        float e0 = __expf(d0 - m), e1 = __expf(d1 - m);
        float sm = e0 + e1;
        sm += __shfl_xor(sm, 1, 64); sm += __shfl_xor(sm, 2, 64);
        sm += __shfl_xor(sm, 4, 64); sm += __shfl_xor(sm, 8, 64);
        float inv = 1.0f / sm;
        float cw0 = e0 * inv, cw1 = e1 * inv;
        csa0 += cw0; csa1 += cw1;
        int ll = w * 16 + lg * 4 + r;
        cw_sh[l15 * 68 + ll] = (short)f2bf(cw0);
        cw_sh[(l15 + 16) * 68 + ll] = (short)f2bf(cw1);
    }
    csa0 += __shfl_xor(csa0, 16, 64); csa0 += __shfl_xor(csa0, 32, 64);
    csa1 += __shfl_xor(csa1, 16, 64); csa1 += __shfl_xor(csa1, 32, 64);
    if (lg == 0) { cs_sh[w][l15] = csa0; cs_sh[w][l15 + 16] = csa1; }
    __syncthreads();
    if (t < Cn) {
        float s = cs_sh[0][t] + cs_sh[1][t] + cs_sh[2][t] + cs_sh[3][t];
        csum_p[((size_t)lt * Bn + b) * Cn + t] = s;
    }
    {
        int cc = t >> 3, slot = t & 7;
        bf16x8 vv;
#pragma unroll
        for (int j = 0; j < 8; ++j) vv[j] = cw_sh[cc * 68 + slot * 8 + j];
        *(bf16x8*)(c_wT + ((size_t)b * Cn + cc) * Ln + l0 + slot * 8) = vv;
    }
}

// ----------------------------------------- x_cb[c][b][d] = c_w^T @ in -------
// grid (8 dt, 64 b), 256 thr / 4 waves; wave covers 32 d (2 x 16).
__global__ __launch_bounds__(256) void k_xc_m(const short* __restrict__ in_T,
                                              const short* __restrict__ c_wT,
                                              short* __restrict__ x_cb) {
    int dt = blockIdx.x, b = blockIdx.y;
    int t = threadIdx.x, w = t >> 6, lane = t & 63;
    int l15 = lane & 15, lg = lane >> 4;
    f32x4 acc[2][2];
#pragma unroll
    for (int h = 0; h < 2; ++h)
#pragma unroll
        for (int dd = 0; dd < 2; ++dd) acc[h][dd] = {0.f, 0.f, 0.f, 0.f};
    const short* A = c_wT + (size_t)b * Cn * Ln;                        // [c][l]
    const short* Bp = in_T + ((size_t)b * Dn + dt * 128 + w * 32) * Ln; // [d][l]
    for (int ks = 0; ks < 16; ++ks) {
        int koff = ks * 32 + lg * 8;
        bf16x8 a0 = *(const bf16x8*)(A + (size_t)l15 * Ln + koff);
        bf16x8 a1 = *(const bf16x8*)(A + (size_t)(l15 + 16) * Ln + koff);
#pragma unroll
        for (int dd = 0; dd < 2; ++dd) {
            bf16x8 bb = *(const bf16x8*)(Bp + (size_t)(dd * 16 + l15) * Ln + koff);
            acc[0][dd] = __builtin_amdgcn_mfma_f32_16x16x32_bf16(a0, bb, acc[0][dd], 0, 0, 0);
            acc[1][dd] = __builtin_amdgcn_mfma_f32_16x16x32_bf16(a1, bb, acc[1][dd], 0, 0, 0);
        }
    }
#pragma unroll
    for (int h = 0; h < 2; ++h)
#pragma unroll
        for (int dd = 0; dd < 2; ++dd)
#pragma unroll
            for (int r = 0; r < 4; ++r) {
                int c = 16 * h + lg * 4 + r;
                int d = dt * 128 + w * 32 + dd * 16 + l15;
                x_cb[((size_t)c * Bn + b) * Dn + d] = (short)f2bf(acc[h][dd][r]);
            }
}

// ---------------------------------------------------------------------------
extern "C" void kernel_launch(void* const* d_in, const int* in_sizes, int n_in,
                              void* d_out, int out_size, void* d_ws, size_t ws_size,
                              hipStream_t stream) {
    const float* in   = (const float*)d_in[0];
    const float* fc_w = (const float*)d_in[1];
    const float* fc_b = (const float*)d_in[2];
    float* out = (float*)d_out;

    char* p = (char*)d_ws;
    auto alloc = [&](size_t bytes) -> char* {
        char* r = p;
        p += (bytes + 255) & ~(size_t)255;
        return r;
    };
    short* in_bf  = (short*)alloc((size_t)Bn * Ln * Dn * 2);   // 64 MB
    short* in_T   = (short*)alloc((size_t)Bn * Dn * Ln * 2);   // 64 MB
    short* fc_wT  = (short*)alloc((size_t)COn * Dn * 2);       // 4 MB
    short* w_vb   = (short*)alloc((size_t)Bn * Cn * Dn * 2);   // 4 MB
    short* c_wT   = (short*)alloc((size_t)Bn * Cn * Ln * 2);   // 2 MB
    short* x_cb   = (short*)alloc((size_t)Cn * Bn * Dn * 2);   // 4 MB
    float* rs_p   = (float*)alloc((size_t)Bn * 8 * Dn * 4);    // 2 MB
    unsigned short* rs_bf = (unsigned short*)alloc((size_t)Bn * Dn * 2);
    float* b_ij   = (float*)alloc((size_t)Bn * Ln * Cn * 4);   // 4 MB
    float* v      = (float*)alloc((size_t)Bn * Cn * On * 4);
    float* bias_v = (float*)alloc((size_t)Bn * Cn * 4);
    float* csum_p = (float*)alloc((size_t)8 * Bn * Cn * 4);

    k_conv<<<dim3(32, Bn), 256, 0, stream>>>(in, in_bf, rs_p);
    k_wprep<<<dim3(16, 8), 256, 0, stream>>>(fc_w, fc_wT);
    k_tr<<<dim3(16, 8, Bn), 256, 0, stream>>>(in_bf, in_T);
    k_rsred<<<dim3(4, Bn), 256, 0, stream>>>(rs_p, rs_bf);
    k_sv3<<<Cn, 256, 0, stream>>>((const short*)rs_bf, csum_p, fc_wT, fc_b,
                                  v, bias_v, 1);
    for (int it = 1; it <= 2; ++it) {
        k_wv2b<<<dim3(8, Cn), 256, 0, stream>>>(v, fc_w, w_vb);
        k_route_m<<<dim3(8, Bn), 256, 0, stream>>>(in_bf, w_vb, bias_v, b_ij,
                                                   c_wT, csum_p, (it == 1) ? 1 : 0);
        k_xc_m<<<dim3(8, Bn), 256, 0, stream>>>(in_T, c_wT, x_cb);
        float* vout = (it == 2) ? out : v;
        k_sv3<<<Cn, 256, 0, stream>>>(x_cb, csum_p, fc_wT, fc_b, vout, bias_v, 0);
    }
}

// Round 6
// 229.389 us; speedup vs baseline: 1.0536x; 1.0536x over previous
//
#include <hip/hip_runtime.h>

// CapsuleLayer: B=64, L=512, D=1024, C=32, O=64, 3 routing iters.
// u_hat never materialized:
//   dots[b,l,c] = in[b,l,:]@w_v[b,c,:] + bias_v[b,c]   (w_v[b,c,d] = sum_o fc_w[d,cO+o] v[b,c,o])
//   s_j[b,c,:]  = x_c[b,c,:]@fc_w[:,c,:] + csum[b,c]*fc_b[c,:]   (x_c = sum_l c_w * in)
// All contractions (dots, x_c, s, w_v) via mfma_f32_16x16x32_bf16 with direct
// global->fragment loads. Layouts: in_bf[b][l][d], in_T[b][d][l],
// fc_wT[co][d], fc_wb[d][co], c_wT[b][c][l], x_cb[c][b][d], v_bf[b][c][o],
// w_vb[b][c][d] (all bf16). Prep fused: k_conv_tr = convert + transpose +
// rowsum in one input pass (u32-packed l-pairs, XOR-swizzled LDS).

namespace {
constexpr int Bn = 64, Ln = 512, Dn = 1024, Cn = 32, On = 64, COn = Cn * On;
}

typedef float f32x4 __attribute__((ext_vector_type(4)));
typedef short bf16x8 __attribute__((ext_vector_type(8)));

static __device__ __forceinline__ unsigned short f2bf(float f) {
    unsigned u = __float_as_uint(f);
    u += 0x7fff + ((u >> 16) & 1);   // RNE
    return (unsigned short)(u >> 16);
}

// ------------------------------------------------------------ conv+tr -------
// One pass over in fp32 [b][l][d] (64 l x 256 d tiles):
//   in_bf bf16 [b][l][d]  +  in_T bf16 [b][d][l]  +  rowsum partials (f32)
// LDS tile [256 d][36 u32] of packed l-pairs; writer col = lp ^ (oct<<2)
// (2-way, free), drain uint4 chunks qs = q ^ ((d>>3)&7) (phase-optimal).
__global__ __launch_bounds__(256) void k_conv_tr(const float* __restrict__ in,
                                                 short* __restrict__ in_bf,
                                                 short* __restrict__ in_T,
                                                 float* __restrict__ rs_p) {
    __shared__ unsigned tile[256 * 36];   // 36864 B
    int b = blockIdx.y;
    int lc = blockIdx.x >> 2, ds = blockIdx.x & 3;
    int l0 = lc * 64, d0 = ds * 256;
    int t = threadIdx.x, w = t >> 6, lane = t & 63;
    int oct = lane & 7;        // d-octet within wave's 64-d slab
    int lpg = lane >> 3;       // l-pair group 0..7
    int dloc = w * 64 + oct * 8;                 // local d of octet base
    const float* src = in + ((size_t)b * Ln + l0) * Dn + d0 + dloc;
    short* dbf = in_bf + ((size_t)b * Ln + l0) * Dn + d0 + dloc;
#pragma unroll
    for (int it = 0; it < 4; ++it) {
        int lp = lpg + 8 * it;
        float4 xa0 = *(const float4*)(src + (size_t)(2 * lp) * Dn);
        float4 xa1 = *(const float4*)(src + (size_t)(2 * lp) * Dn + 4);
        float4 xb0 = *(const float4*)(src + (size_t)(2 * lp + 1) * Dn);
        float4 xb1 = *(const float4*)(src + (size_t)(2 * lp + 1) * Dn + 4);
        unsigned short a[8] = {f2bf(xa0.x), f2bf(xa0.y), f2bf(xa0.z), f2bf(xa0.w),
                               f2bf(xa1.x), f2bf(xa1.y), f2bf(xa1.z), f2bf(xa1.w)};
        unsigned short bb[8] = {f2bf(xb0.x), f2bf(xb0.y), f2bf(xb0.z), f2bf(xb0.w),
                                f2bf(xb1.x), f2bf(xb1.y), f2bf(xb1.z), f2bf(xb1.w)};
        int col = lp ^ (oct << 2);
        unsigned* trow = &tile[(size_t)dloc * 36 + col];
        bf16x8 v0, v1;
#pragma unroll
        for (int k = 0; k < 8; ++k) {
            trow[k * 36] = (unsigned)a[k] | ((unsigned)bb[k] << 16);
            v0[k] = (short)a[k];
            v1[k] = (short)bb[k];
        }
        *(bf16x8*)(dbf + (size_t)(2 * lp) * Dn) = v0;
        *(bf16x8*)(dbf + (size_t)(2 * lp + 1) * Dn) = v1;
    }
    __syncthreads();
#pragma unroll
    for (int r = 0; r < 8; ++r) {
        int idx = t + 256 * r;
        int d = idx >> 3, q = idx & 7;
        int qs = q ^ ((d >> 3) & 7);
        uint4 u = *(const uint4*)(&tile[d * 36 + qs * 4]);
        *(uint4*)(in_T + ((size_t)b * Dn + d0 + d) * Ln + l0 + q * 8) = u;
        float s = __uint_as_float(u.x << 16) + __uint_as_float(u.x & 0xffff0000u)
                + __uint_as_float(u.y << 16) + __uint_as_float(u.y & 0xffff0000u)
                + __uint_as_float(u.z << 16) + __uint_as_float(u.z & 0xffff0000u)
                + __uint_as_float(u.w << 16) + __uint_as_float(u.w & 0xffff0000u);
        s += __shfl_xor(s, 1, 64);
        s += __shfl_xor(s, 2, 64);
        s += __shfl_xor(s, 4, 64);
        if (q == 0) rs_p[((size_t)b * 8 + lc) * Dn + d0 + d] = s;
    }
}

// ---------------------------------------------------------------- wprep -----
// fc_w fp32 [d][co] -> fc_wT bf16 [co][d]  +  fc_wb bf16 [d][co]
__global__ __launch_bounds__(256) void k_wprep(const float* __restrict__ fc_w,
                                               short* __restrict__ fc_wT,
                                               short* __restrict__ fc_wb) {
    __shared__ short tr[64 * 260];      // [d-row][co-col]
    int d0 = blockIdx.x * 64;           // 16
    int co0 = blockIdx.y * 256;         // 8
    int t = threadIdx.x, grp = t >> 6, cq = t & 63;
#pragma unroll
    for (int i = 0; i < 16; ++i) {
        int row = grp + 4 * i;
        float4 x = *(const float4*)(fc_w + (size_t)(d0 + row) * COn + co0 + cq * 4);
        short4 s4 = make_short4((short)f2bf(x.x), (short)f2bf(x.y),
                                (short)f2bf(x.z), (short)f2bf(x.w));
        *(short4*)(&tr[row * 260 + cq * 4]) = s4;
        *(short4*)(fc_wb + (size_t)(d0 + row) * COn + co0 + cq * 4) = s4;
    }
    __syncthreads();
#pragma unroll
    for (int i = 0; i < 8; ++i) {
        int idx = t + 256 * i;
        int corow = idx >> 3, slot = idx & 7;
        bf16x8 v;
#pragma unroll
        for (int j = 0; j < 8; ++j) v[j] = tr[(slot * 8 + j) * 260 + corow];
        *(bf16x8*)(fc_wT + (size_t)(co0 + corow) * Dn + d0 + slot * 8) = v;
    }
}

// ---------------------------------------------------------------- rsred -----
__global__ __launch_bounds__(256) void k_rsred(const float* __restrict__ rs_p,
                                               unsigned short* __restrict__ rs_bf) {
    int b = blockIdx.y, d = blockIdx.x * 256 + threadIdx.x;
    float s = 0.f;
#pragma unroll
    for (int lc = 0; lc < 8; ++lc) s += rs_p[((size_t)b * 8 + lc) * Dn + d];
    rs_bf[b * Dn + d] = f2bf(s * (1.0f / 32.0f));
}

// ------------------------------------------------------- s -> squash -> v ---
// Per-c MFMA GEMM: S[64 b][64 o] = X(64x1024)@W_c(1024x64). Writes v_bf
// (bf16 [b][c][o]) always, plus f32 out when fout != nullptr (final iter).
__global__ __launch_bounds__(256) void k_sv3(const short* __restrict__ xA,
                                             const float* __restrict__ csum_p,
                                             const short* __restrict__ fc_wT,
                                             const float* __restrict__ fc_b,
                                             short* __restrict__ v_bf,
                                             float* __restrict__ fout,
                                             float* __restrict__ bias_v,
                                             int mode0) {
    int c = blockIdx.x;
    int t = threadIdx.x, w = t >> 6, lane = t & 63;
    int l15 = lane & 15, lg = lane >> 4;
    const short* A = mode0 ? xA : (xA + (size_t)c * Bn * Dn);   // [b][d]
    const short* Bw = fc_wT + (size_t)c * On * Dn;              // [o][d]
    f32x4 acc[4];
#pragma unroll
    for (int i = 0; i < 4; ++i) acc[i] = {0.f, 0.f, 0.f, 0.f};
    for (int ks = 0; ks < 32; ++ks) {
        int koff = ks * 32 + lg * 8;
        bf16x8 a = *(const bf16x8*)(A + (size_t)(w * 16 + l15) * Dn + koff);
#pragma unroll
        for (int dt = 0; dt < 4; ++dt) {
            bf16x8 bbf = *(const bf16x8*)(Bw + (size_t)(dt * 16 + l15) * Dn + koff);
            acc[dt] = __builtin_amdgcn_mfma_f32_16x16x32_bf16(a, bbf, acc[dt], 0, 0, 0);
        }
    }
    float fb[4];
#pragma unroll
    for (int dt = 0; dt < 4; ++dt) fb[dt] = fc_b[c * On + dt * 16 + l15];
#pragma unroll
    for (int r = 0; r < 4; ++r) {
        int brow = w * 16 + lg * 4 + r;
        float cs;
        if (mode0) {
            cs = 16.0f;
        } else {
            cs = 0.f;
#pragma unroll
            for (int lt = 0; lt < 8; ++lt) cs += csum_p[((size_t)lt * Bn + brow) * Cn + c];
        }
        float s0 = acc[0][r] + cs * fb[0];
        float s1 = acc[1][r] + cs * fb[1];
        float s2 = acc[2][r] + cs * fb[2];
        float s3 = acc[3][r] + cs * fb[3];
        float sq = s0 * s0 + s1 * s1 + s2 * s2 + s3 * s3;
        sq += __shfl_xor(sq, 1, 64); sq += __shfl_xor(sq, 2, 64);
        sq += __shfl_xor(sq, 4, 64); sq += __shfl_xor(sq, 8, 64);
        float scale = sq / (1.0f + sq) * rsqrtf(sq + 1e-8f);
        float v0 = scale * s0, v1 = scale * s1, v2 = scale * s2, v3 = scale * s3;
        size_t vo = ((size_t)brow * Cn + c) * On;
        v_bf[vo + 0 * 16 + l15] = (short)f2bf(v0);
        v_bf[vo + 1 * 16 + l15] = (short)f2bf(v1);
        v_bf[vo + 2 * 16 + l15] = (short)f2bf(v2);
        v_bf[vo + 3 * 16 + l15] = (short)f2bf(v3);
        if (fout) {
            fout[vo + 0 * 16 + l15] = v0;
            fout[vo + 1 * 16 + l15] = v1;
            fout[vo + 2 * 16 + l15] = v2;
            fout[vo + 3 * 16 + l15] = v3;
        }
        float bv = fb[0] * v0 + fb[1] * v1 + fb[2] * v2 + fb[3] * v3;
        bv += __shfl_xor(bv, 1, 64); bv += __shfl_xor(bv, 2, 64);
        bv += __shfl_xor(bv, 4, 64); bv += __shfl_xor(bv, 8, 64);
        if (l15 == 0) bias_v[brow * Cn + c] = bv;
    }
}

// ------------------------------------------- w_v via MFMA (contract o=64) ---
// grid (4 dslab, 32 c), 256 thr / 4 waves; wave: 64 d x 64 b, K=64.
// A[m=d][k=o] = fc_wb slab (o-contig), B[k=o][n=b] = v_bf rows (o-contig).
__global__ __launch_bounds__(256) void k_wv_m(const short* __restrict__ fc_wb,
                                              const short* __restrict__ v_bf,
                                              short* __restrict__ w_vb) {
    int dsl = blockIdx.x, c = blockIdx.y;
    int t = threadIdx.x, w = t >> 6, lane = t & 63;
    int l15 = lane & 15, lg = lane >> 4;
    int dbase = dsl * 256 + w * 64;
    f32x4 acc[4][4];
#pragma unroll
    for (int i = 0; i < 4; ++i)
#pragma unroll
        for (int j = 0; j < 4; ++j) acc[i][j] = {0.f, 0.f, 0.f, 0.f};
#pragma unroll
    for (int ks = 0; ks < 2; ++ks) {
        int o = ks * 32 + lg * 8;
        bf16x8 bfr[4];
#pragma unroll
        for (int nt = 0; nt < 4; ++nt)
            bfr[nt] = *(const bf16x8*)(v_bf + ((size_t)(nt * 16 + l15) * Cn + c) * On + o);
#pragma unroll
        for (int mt = 0; mt < 4; ++mt) {
            bf16x8 a = *(const bf16x8*)(fc_wb + (size_t)(dbase + mt * 16 + l15) * COn + c * On + o);
#pragma unroll
            for (int nt = 0; nt < 4; ++nt)
                acc[mt][nt] = __builtin_amdgcn_mfma_f32_16x16x32_bf16(a, bfr[nt], acc[mt][nt], 0, 0, 0);
        }
    }
#pragma unroll
    for (int mt = 0; mt < 4; ++mt)
#pragma unroll
        for (int nt = 0; nt < 4; ++nt) {
            int bb = nt * 16 + l15;
            int d = dbase + mt * 16 + lg * 4;
            *(short4*)(w_vb + ((size_t)bb * Cn + c) * Dn + d) =
                make_short4((short)f2bf(acc[mt][nt][0]), (short)f2bf(acc[mt][nt][1]),
                            (short)f2bf(acc[mt][nt][2]), (short)f2bf(acc[mt][nt][3]));
        }
}

// ------------------------------- dots -> b_ij update -> softmax -> c_wT -----
// grid (8 lt, 64 b), 256 thr / 4 waves, wave = 16 l-rows x 32 c. MFMA,
// A-frags straight from in_bf (bf16), B = w_v bf16 rows.
__global__ __launch_bounds__(256) void k_route_m(const short* __restrict__ in_bf,
                                                 const short* __restrict__ w_v,
                                                 const float* __restrict__ bias_v,
                                                 float* __restrict__ b_ij,
                                                 short* __restrict__ c_wT,
                                                 float* __restrict__ csum_p,
                                                 int first) {
    __shared__ short cw_sh[Cn * 68];
    __shared__ float cs_sh[4][Cn];
    int lt = blockIdx.x, b = blockIdx.y;
    int t = threadIdx.x, w = t >> 6, lane = t & 63;
    int l15 = lane & 15, lg = lane >> 4;
    int l0 = lt * 64;
    f32x4 acc0 = {0.f, 0.f, 0.f, 0.f}, acc1 = {0.f, 0.f, 0.f, 0.f};
    const short* Ap = in_bf + ((size_t)b * Ln + l0 + w * 16 + l15) * Dn;
    const short* Bp = w_v + (size_t)b * Cn * Dn;
    for (int ks = 0; ks < 32; ++ks) {
        int koff = ks * 32 + lg * 8;
        bf16x8 a = *(const bf16x8*)(Ap + koff);
        bf16x8 b0 = *(const bf16x8*)(Bp + (size_t)l15 * Dn + koff);
        bf16x8 b1 = *(const bf16x8*)(Bp + (size_t)(l15 + 16) * Dn + koff);
        acc0 = __builtin_amdgcn_mfma_f32_16x16x32_bf16(a, b0, acc0, 0, 0, 0);
        acc1 = __builtin_amdgcn_mfma_f32_16x16x32_bf16(a, b1, acc1, 0, 0, 0);
    }
    float bv0 = bias_v[b * Cn + l15];
    float bv1 = bias_v[b * Cn + l15 + 16];
    float csa0 = 0.f, csa1 = 0.f;
#pragma unroll
    for (int r = 0; r < 4; ++r) {
        int lrow = l0 + w * 16 + lg * 4 + r;
        size_t boff = ((size_t)b * Ln + lrow) * Cn;
        float d0 = acc0[r] + bv0, d1 = acc1[r] + bv1;
        if (!first) { d0 += b_ij[boff + l15]; d1 += b_ij[boff + l15 + 16]; }
        b_ij[boff + l15] = d0;
        b_ij[boff + l15 + 16] = d1;
        float m = fmaxf(d0, d1);
        m = fmaxf(m, __shfl_xor(m, 1, 64)); m = fmaxf(m, __shfl_xor(m, 2, 64));
        m = fmaxf(m, __shfl_xor(m, 4, 64)); m = fmaxf(m, __shfl_xor(m, 8, 64));
        float e0 = __expf(d0 - m), e1 = __expf(d1 - m);
        float sm = e0 + e1;
        sm += __shfl_xor(sm, 1, 64); sm += __shfl_xor(sm, 2, 64);
        sm += __shfl_xor(sm, 4, 64); sm += __shfl_xor(sm, 8, 64);
        float inv = 1.0f / sm;
        float cw0 = e0 * inv, cw1 = e1 * inv;
        csa0 += cw0; csa1 += cw1;
        int ll = w * 16 + lg * 4 + r;
        cw_sh[l15 * 68 + ll] = (short)f2bf(cw0);
        cw_sh[(l15 + 16) * 68 + ll] = (short)f2bf(cw1);
    }
    csa0 += __shfl_xor(csa0, 16, 64); csa0 += __shfl_xor(csa0, 32, 64);
    csa1 += __shfl_xor(csa1, 16, 64); csa1 += __shfl_xor(csa1, 32, 64);
    if (lg == 0) { cs_sh[w][l15] = csa0; cs_sh[w][l15 + 16] = csa1; }
    __syncthreads();
    if (t < Cn) {
        float s = cs_sh[0][t] + cs_sh[1][t] + cs_sh[2][t] + cs_sh[3][t];
        csum_p[((size_t)lt * Bn + b) * Cn + t] = s;
    }
    {
        int cc = t >> 3, slot = t & 7;
        bf16x8 vv;
#pragma unroll
        for (int j = 0; j < 8; ++j) vv[j] = cw_sh[cc * 68 + slot * 8 + j];
        *(bf16x8*)(c_wT + ((size_t)b * Cn + cc) * Ln + l0 + slot * 8) = vv;
    }
}

// ----------------------------------------- x_cb[c][b][d] = c_w^T @ in -------
// grid (8 dt, 64 b), 256 thr / 4 waves; wave covers 32 d (2 x 16).
__global__ __launch_bounds__(256) void k_xc_m(const short* __restrict__ in_T,
                                              const short* __restrict__ c_wT,
                                              short* __restrict__ x_cb) {
    int dt = blockIdx.x, b = blockIdx.y;
    int t = threadIdx.x, w = t >> 6, lane = t & 63;
    int l15 = lane & 15, lg = lane >> 4;
    f32x4 acc[2][2];
#pragma unroll
    for (int h = 0; h < 2; ++h)
#pragma unroll
        for (int dd = 0; dd < 2; ++dd) acc[h][dd] = {0.f, 0.f, 0.f, 0.f};
    const short* A = c_wT + (size_t)b * Cn * Ln;                        // [c][l]
    const short* Bp = in_T + ((size_t)b * Dn + dt * 128 + w * 32) * Ln; // [d][l]
    for (int ks = 0; ks < 16; ++ks) {
        int koff = ks * 32 + lg * 8;
        bf16x8 a0 = *(const bf16x8*)(A + (size_t)l15 * Ln + koff);
        bf16x8 a1 = *(const bf16x8*)(A + (size_t)(l15 + 16) * Ln + koff);
#pragma unroll
        for (int dd = 0; dd < 2; ++dd) {
            bf16x8 bb = *(const bf16x8*)(Bp + (size_t)(dd * 16 + l15) * Ln + koff);
            acc[0][dd] = __builtin_amdgcn_mfma_f32_16x16x32_bf16(a0, bb, acc[0][dd], 0, 0, 0);
            acc[1][dd] = __builtin_amdgcn_mfma_f32_16x16x32_bf16(a1, bb, acc[1][dd], 0, 0, 0);
        }
    }
#pragma unroll
    for (int h = 0; h < 2; ++h)
#pragma unroll
        for (int dd = 0; dd < 2; ++dd)
#pragma unroll
            for (int r = 0; r < 4; ++r) {
                int c = 16 * h + lg * 4 + r;
                int d = dt * 128 + w * 32 + dd * 16 + l15;
                x_cb[((size_t)c * Bn + b) * Dn + d] = (short)f2bf(acc[h][dd][r]);
            }
}

// ---------------------------------------------------------------------------
extern "C" void kernel_launch(void* const* d_in, const int* in_sizes, int n_in,
                              void* d_out, int out_size, void* d_ws, size_t ws_size,
                              hipStream_t stream) {
    const float* in   = (const float*)d_in[0];
    const float* fc_w = (const float*)d_in[1];
    const float* fc_b = (const float*)d_in[2];
    float* out = (float*)d_out;

    char* p = (char*)d_ws;
    auto alloc = [&](size_t bytes) -> char* {
        char* r = p;
        p += (bytes + 255) & ~(size_t)255;
        return r;
    };
    short* in_bf  = (short*)alloc((size_t)Bn * Ln * Dn * 2);   // 64 MB
    short* in_T   = (short*)alloc((size_t)Bn * Dn * Ln * 2);   // 64 MB
    short* fc_wT  = (short*)alloc((size_t)COn * Dn * 2);       // 4 MB
    short* fc_wb  = (short*)alloc((size_t)COn * Dn * 2);       // 4 MB
    short* w_vb   = (short*)alloc((size_t)Bn * Cn * Dn * 2);   // 4 MB
    short* c_wT   = (short*)alloc((size_t)Bn * Cn * Ln * 2);   // 2 MB
    short* x_cb   = (short*)alloc((size_t)Cn * Bn * Dn * 2);   // 4 MB
    short* v_bf   = (short*)alloc((size_t)Bn * Cn * On * 2);   // 256 KB
    float* rs_p   = (float*)alloc((size_t)Bn * 8 * Dn * 4);    // 2 MB
    unsigned short* rs_bf = (unsigned short*)alloc((size_t)Bn * Dn * 2);
    float* b_ij   = (float*)alloc((size_t)Bn * Ln * Cn * 4);   // 4 MB
    float* bias_v = (float*)alloc((size_t)Bn * Cn * 4);
    float* csum_p = (float*)alloc((size_t)8 * Bn * Cn * 4);

    k_conv_tr<<<dim3(32, Bn), 256, 0, stream>>>(in, in_bf, in_T, rs_p);
    k_wprep<<<dim3(16, 8), 256, 0, stream>>>(fc_w, fc_wT, fc_wb);
    k_rsred<<<dim3(4, Bn), 256, 0, stream>>>(rs_p, rs_bf);
    k_sv3<<<Cn, 256, 0, stream>>>((const short*)rs_bf, csum_p, fc_wT, fc_b,
                                  v_bf, nullptr, bias_v, 1);
    for (int it = 1; it <= 2; ++it) {
        k_wv_m<<<dim3(4, Cn), 256, 0, stream>>>(fc_wb, v_bf, w_vb);
        k_route_m<<<dim3(8, Bn), 256, 0, stream>>>(in_bf, w_vb, bias_v, b_ij,
                                                   c_wT, csum_p, (it == 1) ? 1 : 0);
        k_xc_m<<<dim3(8, Bn), 256, 0, stream>>>(in_T, c_wT, x_cb);
        k_sv3<<<Cn, 256, 0, stream>>>(x_cb, csum_p, fc_wT, fc_b,
                                      v_bf, (it == 2) ? out : nullptr, bias_v, 0);
    }
}

// Round 7
// 222.649 us; speedup vs baseline: 1.0855x; 1.0303x over previous
//
#include <hip/hip_runtime.h>

// CapsuleLayer: B=64, L=512, D=1024, C=32, O=64, 3 routing iters.
// u_hat never materialized:
//   dots[b,l,c] = in[b,l,:]@w_v[b,c,:] + bias_v[b,c]   (w_v[b,c,d] = sum_o fc_w[d,cO+o] v[b,c,o])
//   s_j[b,c,:]  = x_c[b,c,:]@fc_w[:,c,:] + csum[b,c]*fc_b[c,:]   (x_c = sum_l c_w * in)
// All contractions (dots, x_c, s, w_v) via mfma_f32_16x16x32_bf16 with direct
// global->fragment loads. Layouts: in_bf[b][l][d], in_T[b][d][l],
// fc_wT[co][d], fc_wb[d][co], c_wT[b][c][l], x_cb[c][b][d], v_bf[b][c][o],
// w_vb[b][c][d] (all bf16). k_conv_tr: one input pass -> convert + transpose
// + rowsum; 64l x 128d tiles, 18.4 KB LDS (8 blocks/CU), all 8 float4 loads
// issued up front (latency-bound fix, R6 post-mortem).

namespace {
constexpr int Bn = 64, Ln = 512, Dn = 1024, Cn = 32, On = 64, COn = Cn * On;
}

typedef float f32x4 __attribute__((ext_vector_type(4)));
typedef short bf16x8 __attribute__((ext_vector_type(8)));

static __device__ __forceinline__ unsigned short f2bf(float f) {
    unsigned u = __float_as_uint(f);
    u += 0x7fff + ((u >> 16) & 1);   // RNE
    return (unsigned short)(u >> 16);
}

// ------------------------------------------------------------ conv+tr -------
// One pass over in fp32 [b][l][d], 64 l x 128 d tiles:
//   in_bf bf16 [b][l][d]  +  in_T bf16 [b][d][l]  +  rowsum partials (f32)
// LDS tile [128 d][36 u32] of packed l-pairs; writer col = lp ^ ((oct&7)<<2)
// (2-way, free), drain uint4 chunks qs = q ^ ((d>>3)&7).
__global__ __launch_bounds__(256) void k_conv_tr(const float* __restrict__ in,
                                                 short* __restrict__ in_bf,
                                                 short* __restrict__ in_T,
                                                 float* __restrict__ rs_p) {
    __shared__ unsigned tile[128 * 36];   // 18432 B -> 8 blocks/CU
    int b = blockIdx.y;
    int lc = blockIdx.x >> 3, ds = blockIdx.x & 7;
    int l0 = lc * 64, d0 = ds * 128;
    int t = threadIdx.x;
    int oct = t & 15;          // 16 octets x 8 d = 128 d
    int lpb = t >> 4;          // l-pair base 0..15
    const float* src = in + ((size_t)b * Ln + l0) * Dn + d0 + oct * 8;
    short* dbf = in_bf + ((size_t)b * Ln + l0) * Dn + d0 + oct * 8;

    // Issue all 8 independent float4 loads first (ILP for HBM latency).
    float4 ld[2][2][2];
#pragma unroll
    for (int it = 0; it < 2; ++it) {
        int lp = lpb + 16 * it;
#pragma unroll
        for (int rr = 0; rr < 2; ++rr) {
            const float* s2 = src + (size_t)(2 * lp + rr) * Dn;
            ld[it][rr][0] = *(const float4*)s2;
            ld[it][rr][1] = *(const float4*)(s2 + 4);
        }
    }
#pragma unroll
    for (int it = 0; it < 2; ++it) {
        int lp = lpb + 16 * it;
        unsigned short a[8] = {f2bf(ld[it][0][0].x), f2bf(ld[it][0][0].y),
                               f2bf(ld[it][0][0].z), f2bf(ld[it][0][0].w),
                               f2bf(ld[it][0][1].x), f2bf(ld[it][0][1].y),
                               f2bf(ld[it][0][1].z), f2bf(ld[it][0][1].w)};
        unsigned short bb[8] = {f2bf(ld[it][1][0].x), f2bf(ld[it][1][0].y),
                                f2bf(ld[it][1][0].z), f2bf(ld[it][1][0].w),
                                f2bf(ld[it][1][1].x), f2bf(ld[it][1][1].y),
                                f2bf(ld[it][1][1].z), f2bf(ld[it][1][1].w)};
        int col = lp ^ ((oct & 7) << 2);
        unsigned* trow = &tile[(size_t)(oct * 8) * 36 + col];
        bf16x8 v0, v1;
#pragma unroll
        for (int k = 0; k < 8; ++k) {
            trow[k * 36] = (unsigned)a[k] | ((unsigned)bb[k] << 16);
            v0[k] = (short)a[k];
            v1[k] = (short)bb[k];
        }
        *(bf16x8*)(dbf + (size_t)(2 * lp) * Dn) = v0;
        *(bf16x8*)(dbf + (size_t)(2 * lp + 1) * Dn) = v1;
    }
    __syncthreads();
#pragma unroll
    for (int r = 0; r < 4; ++r) {
        int idx = t + 256 * r;
        int d = idx >> 3, q = idx & 7;
        int qs = q ^ ((d >> 3) & 7);
        uint4 u = *(const uint4*)(&tile[d * 36 + qs * 4]);
        *(uint4*)(in_T + ((size_t)b * Dn + d0 + d) * Ln + l0 + q * 8) = u;
        float s = __uint_as_float(u.x << 16) + __uint_as_float(u.x & 0xffff0000u)
                + __uint_as_float(u.y << 16) + __uint_as_float(u.y & 0xffff0000u)
                + __uint_as_float(u.z << 16) + __uint_as_float(u.z & 0xffff0000u)
                + __uint_as_float(u.w << 16) + __uint_as_float(u.w & 0xffff0000u);
        s += __shfl_xor(s, 1, 64);
        s += __shfl_xor(s, 2, 64);
        s += __shfl_xor(s, 4, 64);
        if (q == 0) rs_p[((size_t)b * 8 + lc) * Dn + d0 + d] = s;
    }
}

// ---------------------------------------------------------------- wprep -----
// fc_w fp32 [d][co] -> fc_wT bf16 [co][d]  +  fc_wb bf16 [d][co]
__global__ __launch_bounds__(256) void k_wprep(const float* __restrict__ fc_w,
                                               short* __restrict__ fc_wT,
                                               short* __restrict__ fc_wb) {
    __shared__ short tr[64 * 260];      // [d-row][co-col]
    int d0 = blockIdx.x * 64;           // 16
    int co0 = blockIdx.y * 256;         // 8
    int t = threadIdx.x, grp = t >> 6, cq = t & 63;
#pragma unroll
    for (int i = 0; i < 16; ++i) {
        int row = grp + 4 * i;
        float4 x = *(const float4*)(fc_w + (size_t)(d0 + row) * COn + co0 + cq * 4);
        short4 s4 = make_short4((short)f2bf(x.x), (short)f2bf(x.y),
                                (short)f2bf(x.z), (short)f2bf(x.w));
        *(short4*)(&tr[row * 260 + cq * 4]) = s4;
        *(short4*)(fc_wb + (size_t)(d0 + row) * COn + co0 + cq * 4) = s4;
    }
    __syncthreads();
#pragma unroll
    for (int i = 0; i < 8; ++i) {
        int idx = t + 256 * i;
        int corow = idx >> 3, slot = idx & 7;
        bf16x8 v;
#pragma unroll
        for (int j = 0; j < 8; ++j) v[j] = tr[(slot * 8 + j) * 260 + corow];
        *(bf16x8*)(fc_wT + (size_t)(co0 + corow) * Dn + d0 + slot * 8) = v;
    }
}

// ---------------------------------------------------------------- rsred -----
__global__ __launch_bounds__(256) void k_rsred(const float* __restrict__ rs_p,
                                               unsigned short* __restrict__ rs_bf) {
    int b = blockIdx.y, d = blockIdx.x * 256 + threadIdx.x;
    float s = 0.f;
#pragma unroll
    for (int lc = 0; lc < 8; ++lc) s += rs_p[((size_t)b * 8 + lc) * Dn + d];
    rs_bf[b * Dn + d] = f2bf(s * (1.0f / 32.0f));
}

// ------------------------------------------------------- s -> squash -> v ---
// Per-c MFMA GEMM: S[64 b][64 o] = X(64x1024)@W_c(1024x64). Writes v_bf
// (bf16 [b][c][o]) always, plus f32 out when fout != nullptr (final iter).
__global__ __launch_bounds__(256) void k_sv3(const short* __restrict__ xA,
                                             const float* __restrict__ csum_p,
                                             const short* __restrict__ fc_wT,
                                             const float* __restrict__ fc_b,
                                             short* __restrict__ v_bf,
                                             float* __restrict__ fout,
                                             float* __restrict__ bias_v,
                                             int mode0) {
    int c = blockIdx.x;
    int t = threadIdx.x, w = t >> 6, lane = t & 63;
    int l15 = lane & 15, lg = lane >> 4;
    const short* A = mode0 ? xA : (xA + (size_t)c * Bn * Dn);   // [b][d]
    const short* Bw = fc_wT + (size_t)c * On * Dn;              // [o][d]
    f32x4 acc[4];
#pragma unroll
    for (int i = 0; i < 4; ++i) acc[i] = {0.f, 0.f, 0.f, 0.f};
    for (int ks = 0; ks < 32; ++ks) {
        int koff = ks * 32 + lg * 8;
        bf16x8 a = *(const bf16x8*)(A + (size_t)(w * 16 + l15) * Dn + koff);
#pragma unroll
        for (int dt = 0; dt < 4; ++dt) {
            bf16x8 bbf = *(const bf16x8*)(Bw + (size_t)(dt * 16 + l15) * Dn + koff);
            acc[dt] = __builtin_amdgcn_mfma_f32_16x16x32_bf16(a, bbf, acc[dt], 0, 0, 0);
        }
    }
    float fb[4];
#pragma unroll
    for (int dt = 0; dt < 4; ++dt) fb[dt] = fc_b[c * On + dt * 16 + l15];
#pragma unroll
    for (int r = 0; r < 4; ++r) {
        int brow = w * 16 + lg * 4 + r;
        float cs;
        if (mode0) {
            cs = 16.0f;
        } else {
            cs = 0.f;
#pragma unroll
            for (int lt = 0; lt < 8; ++lt) cs += csum_p[((size_t)lt * Bn + brow) * Cn + c];
        }
        float s0 = acc[0][r] + cs * fb[0];
        float s1 = acc[1][r] + cs * fb[1];
        float s2 = acc[2][r] + cs * fb[2];
        float s3 = acc[3][r] + cs * fb[3];
        float sq = s0 * s0 + s1 * s1 + s2 * s2 + s3 * s3;
        sq += __shfl_xor(sq, 1, 64); sq += __shfl_xor(sq, 2, 64);
        sq += __shfl_xor(sq, 4, 64); sq += __shfl_xor(sq, 8, 64);
        float scale = sq / (1.0f + sq) * rsqrtf(sq + 1e-8f);
        float v0 = scale * s0, v1 = scale * s1, v2 = scale * s2, v3 = scale * s3;
        size_t vo = ((size_t)brow * Cn + c) * On;
        v_bf[vo + 0 * 16 + l15] = (short)f2bf(v0);
        v_bf[vo + 1 * 16 + l15] = (short)f2bf(v1);
        v_bf[vo + 2 * 16 + l15] = (short)f2bf(v2);
        v_bf[vo + 3 * 16 + l15] = (short)f2bf(v3);
        if (fout) {
            fout[vo + 0 * 16 + l15] = v0;
            fout[vo + 1 * 16 + l15] = v1;
            fout[vo + 2 * 16 + l15] = v2;
            fout[vo + 3 * 16 + l15] = v3;
        }
        float bv = fb[0] * v0 + fb[1] * v1 + fb[2] * v2 + fb[3] * v3;
        bv += __shfl_xor(bv, 1, 64); bv += __shfl_xor(bv, 2, 64);
        bv += __shfl_xor(bv, 4, 64); bv += __shfl_xor(bv, 8, 64);
        if (l15 == 0) bias_v[brow * Cn + c] = bv;
    }
}

// ------------------------------------------- w_v via MFMA (contract o=64) ---
// grid (4 dslab, 32 c), 256 thr / 4 waves; wave: 64 d x 64 b, K=64.
// A[m=d][k=o] = fc_wb slab (o-contig), B[k=o][n=b] = v_bf rows (o-contig).
__global__ __launch_bounds__(256) void k_wv_m(const short* __restrict__ fc_wb,
                                              const short* __restrict__ v_bf,
                                              short* __restrict__ w_vb) {
    int dsl = blockIdx.x, c = blockIdx.y;
    int t = threadIdx.x, w = t >> 6, lane = t & 63;
    int l15 = lane & 15, lg = lane >> 4;
    int dbase = dsl * 256 + w * 64;
    f32x4 acc[4][4];
#pragma unroll
    for (int i = 0; i < 4; ++i)
#pragma unroll
        for (int j = 0; j < 4; ++j) acc[i][j] = {0.f, 0.f, 0.f, 0.f};
#pragma unroll
    for (int ks = 0; ks < 2; ++ks) {
        int o = ks * 32 + lg * 8;
        bf16x8 bfr[4];
#pragma unroll
        for (int nt = 0; nt < 4; ++nt)
            bfr[nt] = *(const bf16x8*)(v_bf + ((size_t)(nt * 16 + l15) * Cn + c) * On + o);
#pragma unroll
        for (int mt = 0; mt < 4; ++mt) {
            bf16x8 a = *(const bf16x8*)(fc_wb + (size_t)(dbase + mt * 16 + l15) * COn + c * On + o);
#pragma unroll
            for (int nt = 0; nt < 4; ++nt)
                acc[mt][nt] = __builtin_amdgcn_mfma_f32_16x16x32_bf16(a, bfr[nt], acc[mt][nt], 0, 0, 0);
        }
    }
#pragma unroll
    for (int mt = 0; mt < 4; ++mt)
#pragma unroll
        for (int nt = 0; nt < 4; ++nt) {
            int bb = nt * 16 + l15;
            int d = dbase + mt * 16 + lg * 4;
            *(short4*)(w_vb + ((size_t)bb * Cn + c) * Dn + d) =
                make_short4((short)f2bf(acc[mt][nt][0]), (short)f2bf(acc[mt][nt][1]),
                            (short)f2bf(acc[mt][nt][2]), (short)f2bf(acc[mt][nt][3]));
        }
}

// ------------------------------- dots -> b_ij update -> softmax -> c_wT -----
// grid (8 lt, 64 b), 256 thr / 4 waves, wave = 16 l-rows x 32 c. MFMA,
// A-frags straight from in_bf (bf16), B = w_v bf16 rows.
__global__ __launch_bounds__(256) void k_route_m(const short* __restrict__ in_bf,
                                                 const short* __restrict__ w_v,
                                                 const float* __restrict__ bias_v,
                                                 float* __restrict__ b_ij,
                                                 short* __restrict__ c_wT,
                                                 float* __restrict__ csum_p,
                                                 int first) {
    __shared__ short cw_sh[Cn * 68];
    __shared__ float cs_sh[4][Cn];
    int lt = blockIdx.x, b = blockIdx.y;
    int t = threadIdx.x, w = t >> 6, lane = t & 63;
    int l15 = lane & 15, lg = lane >> 4;
    int l0 = lt * 64;
    f32x4 acc0 = {0.f, 0.f, 0.f, 0.f}, acc1 = {0.f, 0.f, 0.f, 0.f};
    const short* Ap = in_bf + ((size_t)b * Ln + l0 + w * 16 + l15) * Dn;
    const short* Bp = w_v + (size_t)b * Cn * Dn;
    for (int ks = 0; ks < 32; ++ks) {
        int koff = ks * 32 + lg * 8;
        bf16x8 a = *(const bf16x8*)(Ap + koff);
        bf16x8 b0 = *(const bf16x8*)(Bp + (size_t)l15 * Dn + koff);
        bf16x8 b1 = *(const bf16x8*)(Bp + (size_t)(l15 + 16) * Dn + koff);
        acc0 = __builtin_amdgcn_mfma_f32_16x16x32_bf16(a, b0, acc0, 0, 0, 0);
        acc1 = __builtin_amdgcn_mfma_f32_16x16x32_bf16(a, b1, acc1, 0, 0, 0);
    }
    float bv0 = bias_v[b * Cn + l15];
    float bv1 = bias_v[b * Cn + l15 + 16];
    float csa0 = 0.f, csa1 = 0.f;
#pragma unroll
    for (int r = 0; r < 4; ++r) {
        int lrow = l0 + w * 16 + lg * 4 + r;
        size_t boff = ((size_t)b * Ln + lrow) * Cn;
        float d0 = acc0[r] + bv0, d1 = acc1[r] + bv1;
        if (!first) { d0 += b_ij[boff + l15]; d1 += b_ij[boff + l15 + 16]; }
        b_ij[boff + l15] = d0;
        b_ij[boff + l15 + 16] = d1;
        float m = fmaxf(d0, d1);
        m = fmaxf(m, __shfl_xor(m, 1, 64)); m = fmaxf(m, __shfl_xor(m, 2, 64));
        m = fmaxf(m, __shfl_xor(m, 4, 64)); m = fmaxf(m, __shfl_xor(m, 8, 64));
        float e0 = __expf(d0 - m), e1 = __expf(d1 - m);
        float sm = e0 + e1;
        sm += __shfl_xor(sm, 1, 64); sm += __shfl_xor(sm, 2, 64);
        sm += __shfl_xor(sm, 4, 64); sm += __shfl_xor(sm, 8, 64);
        float inv = 1.0f / sm;
        float cw0 = e0 * inv, cw1 = e1 * inv;
        csa0 += cw0; csa1 += cw1;
        int ll = w * 16 + lg * 4 + r;
        cw_sh[l15 * 68 + ll] = (short)f2bf(cw0);
        cw_sh[(l15 + 16) * 68 + ll] = (short)f2bf(cw1);
    }
    csa0 += __shfl_xor(csa0, 16, 64); csa0 += __shfl_xor(csa0, 32, 64);
    csa1 += __shfl_xor(csa1, 16, 64); csa1 += __shfl_xor(csa1, 32, 64);
    if (lg == 0) { cs_sh[w][l15] = csa0; cs_sh[w][l15 + 16] = csa1; }
    __syncthreads();
    if (t < Cn) {
        float s = cs_sh[0][t] + cs_sh[1][t] + cs_sh[2][t] + cs_sh[3][t];
        csum_p[((size_t)lt * Bn + b) * Cn + t] = s;
    }
    {
        int cc = t >> 3, slot = t & 7;
        bf16x8 vv;
#pragma unroll
        for (int j = 0; j < 8; ++j) vv[j] = cw_sh[cc * 68 + slot * 8 + j];
        *(bf16x8*)(c_wT + ((size_t)b * Cn + cc) * Ln + l0 + slot * 8) = vv;
    }
}

// ----------------------------------------- x_cb[c][b][d] = c_w^T @ in -------
// grid (8 dt, 64 b), 256 thr / 4 waves; wave covers 32 d (2 x 16).
__global__ __launch_bounds__(256) void k_xc_m(const short* __restrict__ in_T,
                                              const short* __restrict__ c_wT,
                                              short* __restrict__ x_cb) {
    int dt = blockIdx.x, b = blockIdx.y;
    int t = threadIdx.x, w = t >> 6, lane = t & 63;
    int l15 = lane & 15, lg = lane >> 4;
    f32x4 acc[2][2];
#pragma unroll
    for (int h = 0; h < 2; ++h)
#pragma unroll
        for (int dd = 0; dd < 2; ++dd) acc[h][dd] = {0.f, 0.f, 0.f, 0.f};
    const short* A = c_wT + (size_t)b * Cn * Ln;                        // [c][l]
    const short* Bp = in_T + ((size_t)b * Dn + dt * 128 + w * 32) * Ln; // [d][l]
    for (int ks = 0; ks < 16; ++ks) {
        int koff = ks * 32 + lg * 8;
        bf16x8 a0 = *(const bf16x8*)(A + (size_t)l15 * Ln + koff);
        bf16x8 a1 = *(const bf16x8*)(A + (size_t)(l15 + 16) * Ln + koff);
#pragma unroll
        for (int dd = 0; dd < 2; ++dd) {
            bf16x8 bb = *(const bf16x8*)(Bp + (size_t)(dd * 16 + l15) * Ln + koff);
            acc[0][dd] = __builtin_amdgcn_mfma_f32_16x16x32_bf16(a0, bb, acc[0][dd], 0, 0, 0);
            acc[1][dd] = __builtin_amdgcn_mfma_f32_16x16x32_bf16(a1, bb, acc[1][dd], 0, 0, 0);
        }
    }
#pragma unroll
    for (int h = 0; h < 2; ++h)
#pragma unroll
        for (int dd = 0; dd < 2; ++dd)
#pragma unroll
            for (int r = 0; r < 4; ++r) {
                int c = 16 * h + lg * 4 + r;
                int d = dt * 128 + w * 32 + dd * 16 + l15;
                x_cb[((size_t)c * Bn + b) * Dn + d] = (short)f2bf(acc[h][dd][r]);
            }
}

// ---------------------------------------------------------------------------
extern "C" void kernel_launch(void* const* d_in, const int* in_sizes, int n_in,
                              void* d_out, int out_size, void* d_ws, size_t ws_size,
                              hipStream_t stream) {
    const float* in   = (const float*)d_in[0];
    const float* fc_w = (const float*)d_in[1];
    const float* fc_b = (const float*)d_in[2];
    float* out = (float*)d_out;

    char* p = (char*)d_ws;
    auto alloc = [&](size_t bytes) -> char* {
        char* r = p;
        p += (bytes + 255) & ~(size_t)255;
        return r;
    };
    short* in_bf  = (short*)alloc((size_t)Bn * Ln * Dn * 2);   // 64 MB
    short* in_T   = (short*)alloc((size_t)Bn * Dn * Ln * 2);   // 64 MB
    short* fc_wT  = (short*)alloc((size_t)COn * Dn * 2);       // 4 MB
    short* fc_wb  = (short*)alloc((size_t)COn * Dn * 2);       // 4 MB
    short* w_vb   = (short*)alloc((size_t)Bn * Cn * Dn * 2);   // 4 MB
    short* c_wT   = (short*)alloc((size_t)Bn * Cn * Ln * 2);   // 2 MB
    short* x_cb   = (short*)alloc((size_t)Cn * Bn * Dn * 2);   // 4 MB
    short* v_bf   = (short*)alloc((size_t)Bn * Cn * On * 2);   // 256 KB
    float* rs_p   = (float*)alloc((size_t)Bn * 8 * Dn * 4);    // 2 MB
    unsigned short* rs_bf = (unsigned short*)alloc((size_t)Bn * Dn * 2);
    float* b_ij   = (float*)alloc((size_t)Bn * Ln * Cn * 4);   // 4 MB
    float* bias_v = (float*)alloc((size_t)Bn * Cn * 4);
    float* csum_p = (float*)alloc((size_t)8 * Bn * Cn * 4);

    k_conv_tr<<<dim3(64, Bn), 256, 0, stream>>>(in, in_bf, in_T, rs_p);
    k_wprep<<<dim3(16, 8), 256, 0, stream>>>(fc_w, fc_wT, fc_wb);
    k_rsred<<<dim3(4, Bn), 256, 0, stream>>>(rs_p, rs_bf);
    k_sv3<<<Cn, 256, 0, stream>>>((const short*)rs_bf, csum_p, fc_wT, fc_b,
                                  v_bf, nullptr, bias_v, 1);
    for (int it = 1; it <= 2; ++it) {
        k_wv_m<<<dim3(4, Cn), 256, 0, stream>>>(fc_wb, v_bf, w_vb);
        k_route_m<<<dim3(8, Bn), 256, 0, stream>>>(in_bf, w_vb, bias_v, b_ij,
                                                   c_wT, csum_p, (it == 1) ? 1 : 0);
        k_xc_m<<<dim3(8, Bn), 256, 0, stream>>>(in_T, c_wT, x_cb);
        k_sv3<<<Cn, 256, 0, stream>>>(x_cb, csum_p, fc_wT, fc_b,
                                      v_bf, (it == 2) ? out : nullptr, bias_v, 0);
    }
}